// Round 1
// baseline (203.071 us; speedup 1.0000x reference)
//
#include <hip/hip_runtime.h>
#include <hip/hip_bf16.h>

// Problem dims (fixed by the reference)
constexpr int B_  = 4;
constexpr int S_  = 2048;
constexpr int D_  = 512;
constexpr int H_  = 8;
constexpr int HD_ = 64;
constexpr int M_  = B_ * S_;   // 8192

constexpr float LOG2E = 1.4426950408889634f;

typedef __attribute__((ext_vector_type(8))) short short8v;            // 8 bf16 (4 VGPR) MFMA operand
typedef __attribute__((ext_vector_type(8))) unsigned short ushort8v;  // 16B staging chunk
typedef __attribute__((ext_vector_type(4))) float float4v;            // MFMA C/D

__device__ __forceinline__ unsigned short f2bf(float x) {  // RNE fp32->bf16
    unsigned u = __builtin_bit_cast(unsigned, x);
    u += 0x7fffu + ((u >> 16) & 1u);
    return (unsigned short)(u >> 16);
}
__device__ __forceinline__ unsigned short f2bf_trunc(float x) {  // truncate (1 op)
    return (unsigned short)(__builtin_bit_cast(unsigned, x) >> 16);
}
__device__ __forceinline__ float bf2f(unsigned short h) {
    return __builtin_bit_cast(float, ((unsigned)h) << 16);
}
__device__ __forceinline__ float fast_exp2(float x) {
#if __has_builtin(__builtin_amdgcn_exp2f)
    return __builtin_amdgcn_exp2f(x);
#else
    return exp2f(x);
#endif
}
// async global->LDS, 16B per lane; lds dest = wave-uniform base + lane*16
__device__ __forceinline__ void gload_lds16(const void* g, void* lds) {
    __builtin_amdgcn_global_load_lds((const __attribute__((address_space(1))) unsigned*)g,
                                     (__attribute__((address_space(3))) unsigned*)lds, 16, 0, 0);
}

// ---------------------------------------------------------------------------
// Prepass: build bf16 operands (R8 version).
//   Xp  [8192][1024]: cols [0:512)=hi(x), [512:1024)=lo(x)
//   Wh  [1536][512] : hi(w_qkv);  Wlq [512][512]: lo(w_q);  Wob: hi(w_out)
// ---------------------------------------------------------------------------
__global__ __launch_bounds__(256) void prepass(const float* __restrict__ x,
                                               const float* __restrict__ wqkv,
                                               const float* __restrict__ wout,
                                               unsigned short* __restrict__ Xp,
                                               unsigned short* __restrict__ Wh,
                                               unsigned short* __restrict__ Wlq,
                                               unsigned short* __restrict__ Wob) {
    const int bid = blockIdx.x, t = threadIdx.x;
    if (bid < 2048) {                      // x
        const int flat = bid * 256 + t;
        const int m = flat >> 6, c = (flat & 63) * 8;
        const float4 a = *(const float4*)&x[(size_t)m * 512 + c];
        const float4 b = *(const float4*)&x[(size_t)m * 512 + c + 4];
        const float v[8] = {a.x, a.y, a.z, a.w, b.x, b.y, b.z, b.w};
        ushort8v hi, lo;
#pragma unroll
        for (int i = 0; i < 8; ++i) {
            const unsigned short h = f2bf(v[i]);
            hi[i] = h; lo[i] = f2bf(v[i] - bf2f(h));
        }
        *(ushort8v*)&Xp[(size_t)m * 1024 + c]       = hi;
        *(ushort8v*)&Xp[(size_t)m * 1024 + 512 + c] = lo;
    } else if (bid < 2048 + 384) {         // w_qkv
        const int flat = (bid - 2048) * 256 + t;
        const int e = flat >> 6, c = (flat & 63) * 8;
        const float4 a = *(const float4*)&wqkv[(size_t)e * 512 + c];
        const float4 b = *(const float4*)&wqkv[(size_t)e * 512 + c + 4];
        const float v[8] = {a.x, a.y, a.z, a.w, b.x, b.y, b.z, b.w};
        ushort8v hi, lo;
#pragma unroll
        for (int i = 0; i < 8; ++i) {
            const unsigned short h = f2bf(v[i]);
            hi[i] = h; lo[i] = f2bf(v[i] - bf2f(h));
        }
        *(ushort8v*)&Wh[(size_t)e * 512 + c] = hi;
        if (e < 512) *(ushort8v*)&Wlq[(size_t)e * 512 + c] = lo;
    } else {                               // w_out
        const int flat = (bid - 2432) * 256 + t;
        const int e = flat >> 6, c = (flat & 63) * 8;
        const float4 a = *(const float4*)&wout[(size_t)e * 512 + c];
        const float4 b = *(const float4*)&wout[(size_t)e * 512 + c + 4];
        const float v[8] = {a.x, a.y, a.z, a.w, b.x, b.y, b.z, b.w};
        ushort8v hi;
#pragma unroll
        for (int i = 0; i < 8; ++i) hi[i] = f2bf(v[i]);
        *(ushort8v*)&Wob[(size_t)e * 512 + c] = hi;
    }
}

// ---------------------------------------------------------------------------
// GEMM1 (QKV projection): 128x64 tiles, BK=64, dbuf+prefetch, 1 barrier/iter.
// LDS 48 KB -> 3 blocks/CU; grid (32,64)=2048 blocks (8 blocks/CU of work).
// Slices: x>>3 = 0:qcorr(K=1024, dispatched first) 1:qmain 2:k 3:v (K=512).
// e0 = (x&7)*64 within the 512-wide segment.
// Wave layout: wrow=(wv>>1)*64, wcol=(wv&1)*32; acc[4][2].
// vblk: acc[mt][nt] = mfma(A=bf[nt], B=af[mt]) => D rows = e, cols = m.
// ---------------------------------------------------------------------------
__global__ __launch_bounds__(256, 3) void gemm_qkv(const unsigned short* __restrict__ Xp,
                                                   const unsigned short* __restrict__ Wh,
                                                   const unsigned short* __restrict__ Wlq,
                                                   unsigned short* __restrict__ QmH,
                                                   unsigned short* __restrict__ QmL,
                                                   unsigned short* __restrict__ Cc,
                                                   unsigned short* __restrict__ KH,
                                                   unsigned short* __restrict__ VT) {
    __shared__ unsigned short Asm[2][128 * 64];   // 32 KB
    __shared__ unsigned short Bsm[2][64 * 64];    // 16 KB
    const int t = threadIdx.x, wv = t >> 6, lane = t & 63;
    const int fm = lane & 15, fq = lane >> 4;
    const int m0 = blockIdx.y * 128;
    const int x  = blockIdx.x;
    const int slice = x >> 3;            // 0=qcorr 1=qmain 2=k 3=v
    const int e0 = (x & 7) * 64;         // within the 512-wide segment
    const bool vblk = (slice == 3);
    const int kiters = (slice == 0) ? 16 : 8;
    const int wrow = (wv >> 1) * 64, wcol = (wv & 1) * 32;

    const unsigned short* BbaseWh =
        Wh + (size_t)(e0 + (slice == 2 ? 512 : (slice == 3 ? 1024 : 0))) * 512;
    const unsigned short* BbaseWlq = Wlq + (size_t)e0 * 512;

    const int srow = t >> 3;     // 0..31; +32*i extends
    const int skb0 = t & 7;

    float4v acc[4][2];
#pragma unroll
    for (int i = 0; i < 4; ++i)
#pragma unroll
        for (int j = 0; j < 2; ++j) acc[i][j] = (float4v){0.f, 0.f, 0.f, 0.f};

    // prologue: stage tile kk=0 into buf 0
    {
        const int aoff = (slice == 0) ? 512 : 0;   // qcorr pass0 uses XL
#pragma unroll
        for (int i = 0; i < 4; ++i) {
            const int row = srow + 32 * i;
            const int kb = skb0 ^ (row & 7);
            gload_lds16(Xp + (size_t)(m0 + row) * 1024 + aoff + kb * 8,
                        &Asm[0][(wv * 64 + 256 * i) * 8]);
        }
#pragma unroll
        for (int i = 0; i < 2; ++i) {
            const int row = srow + 32 * i;
            const int kb = skb0 ^ (row & 7);
            gload_lds16(BbaseWh + (size_t)row * 512 + kb * 8,
                        &Bsm[0][(wv * 64 + 256 * i) * 8]);
        }
    }

    for (int kk = 0; kk < kiters; ++kk) {
        __syncthreads();   // tile kk DMA complete; buf[(kk+1)&1] free

        if (kk + 1 < kiters) {     // prefetch tile kk+1 (overlaps compute of kk)
            const int nk = kk + 1;
            const int pass = nk >> 3;
            const int k0n = (nk & 7) * 64;
            const int nbuf = nk & 1;
            const int aoff = (slice == 0 && pass == 0) ? 512 : 0;
            const unsigned short* Bp = (slice == 0 && pass == 1) ? BbaseWlq : BbaseWh;
#pragma unroll
            for (int i = 0; i < 4; ++i) {
                const int row = srow + 32 * i;
                const int kb = skb0 ^ (row & 7);
                gload_lds16(Xp + (size_t)(m0 + row) * 1024 + aoff + k0n + kb * 8,
                            &Asm[nbuf][(wv * 64 + 256 * i) * 8]);
            }
#pragma unroll
            for (int i = 0; i < 2; ++i) {
                const int row = srow + 32 * i;
                const int kb = skb0 ^ (row & 7);
                gload_lds16(Bp + (size_t)row * 512 + k0n + kb * 8,
                            &Bsm[nbuf][(wv * 64 + 256 * i) * 8]);
            }
        }

        const int buf = kk & 1;
#pragma unroll
        for (int ks = 0; ks < 2; ++ks) {
            short8v af[4], bf[2];
#pragma unroll
            for (int mt = 0; mt < 4; ++mt) {
                const int row = wrow + mt * 16 + fm;
                af[mt] = *(const short8v*)&Asm[buf][row * 64 + 8 * ((4 * ks + fq) ^ (row & 7))];
            }
#pragma unroll
            for (int nt = 0; nt < 2; ++nt) {
                const int row = wcol + nt * 16 + fm;
                bf[nt] = *(const short8v*)&Bsm[buf][row * 64 + 8 * ((4 * ks + fq) ^ (row & 7))];
            }
            if (vblk) {
#pragma unroll
                for (int mt = 0; mt < 4; ++mt)
#pragma unroll
                    for (int nt = 0; nt < 2; ++nt)
                        acc[mt][nt] = __builtin_amdgcn_mfma_f32_16x16x32_bf16(bf[nt], af[mt], acc[mt][nt], 0, 0, 0);
            } else {
#pragma unroll
                for (int mt = 0; mt < 4; ++mt)
#pragma unroll
                    for (int nt = 0; nt < 2; ++nt)
                        acc[mt][nt] = __builtin_amdgcn_mfma_f32_16x16x32_bf16(af[mt], bf[nt], acc[mt][nt], 0, 0, 0);
            }
        }
    }

    if (slice == 1) {
        // qmain: hi/lo split store (acc rows = m-block mt, cols = e-block nt)
#pragma unroll
        for (int mt = 0; mt < 4; ++mt)
#pragma unroll
            for (int nt = 0; nt < 2; ++nt) {
                const int e = e0 + wcol + nt * 16 + fm;
                const int h = e >> 6, hd = e & 63;
#pragma unroll
                for (int r = 0; r < 4; ++r) {
                    const int m = m0 + wrow + mt * 16 + 4 * fq + r;
                    const int b = m >> 11, s = m & 2047;
                    const float v = acc[mt][nt][r];
                    const unsigned short hh = f2bf(v);
                    const size_t idx = ((size_t)(b * 8 + h) * 2048 + s) * 64 + hd;
                    QmH[idx] = hh;
                    QmL[idx] = f2bf(v - bf2f(hh));
                }
            }
    } else if (slice == 0 || slice == 2) {
        // qcorr / k: single bf16 store
        unsigned short* __restrict__ dst = (slice == 0) ? Cc : KH;
#pragma unroll
        for (int mt = 0; mt < 4; ++mt)
#pragma unroll
            for (int nt = 0; nt < 2; ++nt) {
                const int e = e0 + wcol + nt * 16 + fm;
                const int h = e >> 6, hd = e & 63;
#pragma unroll
                for (int r = 0; r < 4; ++r) {
                    const int m = m0 + wrow + mt * 16 + 4 * fq + r;
                    const int b = m >> 11, s = m & 2047;
                    dst[((size_t)(b * 8 + h) * 2048 + s) * 64 + hd] = f2bf(acc[mt][nt][r]);
                }
            }
    } else {
        // v: acc[mt][nt] rows = e-block nt (4fq+r), cols = m-block mt (fm)
#pragma unroll
        for (int nt = 0; nt < 2; ++nt)
#pragma unroll
            for (int r = 0; r < 4; ++r) {
                const int e = e0 + wcol + nt * 16 + 4 * fq + r;
                const int h = e >> 6, hd = e & 63;
#pragma unroll
                for (int mt = 0; mt < 4; ++mt) {
                    const int m = m0 + wrow + mt * 16 + fm;
                    const int b = m >> 11, s = m & 2047;
                    VT[((size_t)(b * 8 + h) * 64 + hd) * 2048 + s] = f2bf(acc[mt][nt][r]);
                }
            }
    }
}

// ---------------------------------------------------------------------------
// MFMA flash attention v2 (occupancy-focused restructure).
// Block = (bh, 64 q-rows); grid (32,32)=1024 blocks = 4 blocks/CU.
// LDS exactly 40 KB (KsH 16K + Vs 16K + Ph 8K) -> 4 resident -> 16 waves/CU
// (was: 512 blocks, 50 KB, 2 blocks/CU, 8 waves/CU, Occupancy 21%).
// Swapped QK^T: accS = mfma(A=kf, B=qf) => lane holds S[q=fm][j=st*16+4fq+r];
// the 4 r-values are j-contiguous so P packs to 2 dwords and stores as ONE
// ds_write_b64 per st (4/iter) instead of 32 scalar ds_write_b16/iter.
// Ph[16][64] wave-private, XOR-swizzled c^=((fm&7)<<3): bijective per aligned
// 8-short block; b64 writes 4-way/2-word (BW-optimal), b128 reads 8 words/bank
// (BW-optimal). One barrier per j-iter + dbuf K/V DMA prefetch, as before.
// ---------------------------------------------------------------------------
__global__ __launch_bounds__(256, 4) void attn(const unsigned short* __restrict__ QmHp,
                                               const unsigned short* __restrict__ QmLp,
                                               const unsigned short* __restrict__ Ccp,
                                               const unsigned short* __restrict__ KHp,
                                               const unsigned short* __restrict__ VTp,
                                               unsigned short* __restrict__ OB) {
    __shared__ unsigned short KsH[2][64 * 64];   // 16 KB
    __shared__ unsigned short Vs[2][64 * 64];    // 16 KB
    __shared__ unsigned short Ph[4][16 * 64];    // 8 KB, wave-private, XOR-swizzled
    const int t = threadIdx.x, wv = t >> 6, lane = t & 63;
    const int fm = lane & 15, fq = lane >> 4;
    const int bh = blockIdx.y, q0 = blockIdx.x * 64;

    const unsigned short* qmh = QmHp + (size_t)bh * S_ * 64;
    const unsigned short* qml = QmLp + (size_t)bh * S_ * 64;
    const unsigned short* qcc = Ccp  + (size_t)bh * S_ * 64;
    const unsigned short* kh  = KHp  + (size_t)bh * S_ * 64;
    const unsigned short* vt  = VTp  + (size_t)bh * 64 * S_;

    const int srow = t >> 3;
    const int skb0 = t & 7;

    // prologue: stage K/V tile jt=0 into buf 0
#pragma unroll
    for (int i = 0; i < 2; ++i) {
        const int row = srow + 32 * i;
        const int kb = skb0 ^ (row & 7);
        const int dst = (wv * 64 + 256 * i) * 8;
        gload_lds16(kh + (size_t)row * 64 + kb * 8, &KsH[0][dst]);
        gload_lds16(vt + (size_t)row * S_ + kb * 8, &Vs[0][dst]);
    }

    // Q fragment for this wave's 16 q-rows (q = q0 + wv*16 + fm):
    // q = (Qm + C) * log2e, split hi/lo.  (B-operand layout == old A layout.)
    short8v qfh[2], qfl[2];
    {
        const int qrow = q0 + wv * 16 + fm;
#pragma unroll
        for (int t2 = 0; t2 < 2; ++t2) {
            const size_t off = (size_t)qrow * 64 + t2 * 32 + fq * 8;
            const ushort8v mh = *(const ushort8v*)&qmh[off];
            const ushort8v ml = *(const ushort8v*)&qml[off];
            const ushort8v cc = *(const ushort8v*)&qcc[off];
#pragma unroll
            for (int i = 0; i < 8; ++i) {
                const float v = (bf2f(mh[i]) + bf2f(ml[i]) + bf2f(cc[i])) * LOG2E;
                const unsigned short hh = f2bf(v);
                qfh[t2][i] = (short)hh;
                qfl[t2][i] = (short)f2bf(v - bf2f(hh));
            }
        }
    }

    float4v accO[4];
#pragma unroll
    for (int dt = 0; dt < 4; ++dt) accO[dt] = (float4v){0.f, 0.f, 0.f, 0.f};
    float lsum[4] = {0.f, 0.f, 0.f, 0.f};

    const int phx = (fm & 7) << 3;   // Ph XOR swizzle (bits >=3: preserves b64/b128 blocks)
    unsigned short* phw = &Ph[wv][0];

    for (int jt = 0; jt < 32; ++jt) {
        __syncthreads();   // tile jt DMA complete (barrier drains vmcnt); buf[(jt+1)&1] free

        if (jt + 1 < 32) {
            const int j0n = (jt + 1) * 64;
            const int nbuf = (jt + 1) & 1;
#pragma unroll
            for (int i = 0; i < 2; ++i) {
                const int row = srow + 32 * i;
                const int kb = skb0 ^ (row & 7);
                const int dst = (wv * 64 + 256 * i) * 8;
                gload_lds16(kh + (size_t)(j0n + row) * 64 + kb * 8, &KsH[nbuf][dst]);
                gload_lds16(vt + (size_t)row * S_ + j0n + kb * 8, &Vs[nbuf][dst]);
            }
        }
        const int buf = jt & 1;

        // S^T = K Q^T (swapped operands): lane holds S[q=fm][j=st*16+4fq+r]
        float4v accS[4];
#pragma unroll
        for (int st = 0; st < 4; ++st) accS[st] = (float4v){0.f, 0.f, 0.f, 0.f};
#pragma unroll
        for (int t2 = 0; t2 < 2; ++t2)
#pragma unroll
            for (int st = 0; st < 4; ++st) {
                const int row = st * 16 + fm;
                const short8v kf = *(const short8v*)&KsH[buf][row * 64 + 8 * ((4 * t2 + fq) ^ (row & 7))];
                accS[st] = __builtin_amdgcn_mfma_f32_16x16x32_bf16(kf, qfh[t2], accS[st], 0, 0, 0);
                accS[st] = __builtin_amdgcn_mfma_f32_16x16x32_bf16(kf, qfl[t2], accS[st], 0, 0, 0);
            }

        // P = exp2(S); accumulate l; pack 4 j-contiguous bf16 -> one b64 store
#pragma unroll
        for (int st = 0; st < 4; ++st) {
            float p[4];
#pragma unroll
            for (int r = 0; r < 4; ++r) {
                p[r] = fast_exp2(accS[st][r]);
                lsum[r] += p[r];
            }
            const unsigned u0 = __builtin_bit_cast(unsigned, p[0]);
            const unsigned u1 = __builtin_bit_cast(unsigned, p[1]);
            const unsigned u2 = __builtin_bit_cast(unsigned, p[2]);
            const unsigned u3 = __builtin_bit_cast(unsigned, p[3]);
            uint2 w;
            w.x = (u1 & 0xffff0000u) | (u0 >> 16);   // trunc bf16 pair (j, j+1)
            w.y = (u3 & 0xffff0000u) | (u2 >> 16);   // trunc bf16 pair (j+2, j+3)
            *(uint2*)&phw[fm * 64 + ((st * 16 + 4 * fq) ^ phx)] = w;
        }

        // O += P V  (A-fragment: P[q=fm][j=t2*32+8fq..+7] = one b128 read)
#pragma unroll
        for (int t2 = 0; t2 < 2; ++t2) {
            const short8v pa = *(const short8v*)&phw[fm * 64 + ((t2 * 32 + 8 * fq) ^ phx)];
#pragma unroll
            for (int dt = 0; dt < 4; ++dt) {
                const int vrow = dt * 16 + fm;
                const short8v vf = *(const short8v*)&Vs[buf][vrow * 64 + 8 * ((4 * t2 + fq) ^ (vrow & 7))];
                accO[dt] = __builtin_amdgcn_mfma_f32_16x16x32_bf16(pa, vf, accO[dt], 0, 0, 0);
            }
        }
    }

    // l total for q=fm lives split across fq groups: butterfly over lane bits 4,5
    float ls = (lsum[0] + lsum[1]) + (lsum[2] + lsum[3]);
    ls += __shfl_xor(ls, 16);
    ls += __shfl_xor(ls, 32);

    // epilogue: accO[dt][r] = O[q_local=4fq+r][d=dt*16+fm]; fetch l[4fq+r]
    const int b = bh >> 3, h = bh & 7;
#pragma unroll
    for (int r = 0; r < 4; ++r) {
        const float inv = 1.f / __shfl(ls, 4 * fq + r);
        const int q = q0 + wv * 16 + 4 * fq + r;
#pragma unroll
        for (int dt = 0; dt < 4; ++dt)
            OB[((size_t)(b * 2048 + q)) * 512 + h * 64 + dt * 16 + fm] =
                f2bf(accO[dt][r] * inv);
    }
}

// ---------------------------------------------------------------------------
// GEMM2 (out projection), R8 version: 128x64 tile, dbuf + prefetch.
// ---------------------------------------------------------------------------
__global__ __launch_bounds__(256) void gemm_out(const unsigned short* __restrict__ OB,
                                                const unsigned short* __restrict__ Wob,
                                                float* __restrict__ out) {
    __shared__ unsigned short Asm[2][128 * 64];
    __shared__ unsigned short Bsm[2][64 * 64];
    const int t = threadIdx.x, wv = t >> 6, lane = t & 63;
    const int fm = lane & 15, fq = lane >> 4;
    const int m0 = blockIdx.y * 128, e0 = blockIdx.x * 64;
    const int wrow = (wv & 1) * 64, wcol = (wv >> 1) * 32;

    const int srow = t >> 3;
    const int skb0 = t & 7;

    float4v acc[4][2];
#pragma unroll
    for (int i = 0; i < 4; ++i)
#pragma unroll
        for (int j = 0; j < 2; ++j) acc[i][j] = (float4v){0.f, 0.f, 0.f, 0.f};

    // prologue: stage k0=0
#pragma unroll
    for (int i = 0; i < 4; ++i) {
        const int row = srow + 32 * i;
        const int kb = skb0 ^ (row & 7);
        gload_lds16(OB + (size_t)(m0 + row) * 512 + kb * 8,
                    &Asm[0][(wv * 64 + 256 * i) * 8]);
    }
#pragma unroll
    for (int i = 0; i < 2; ++i) {
        const int row = srow + 32 * i;
        const int kb = skb0 ^ (row & 7);
        gload_lds16(Wob + (size_t)(e0 + row) * 512 + kb * 8,
                    &Bsm[0][(wv * 64 + 256 * i) * 8]);
    }

    for (int kk = 0; kk < 8; ++kk) {
        __syncthreads();
        if (kk + 1 < 8) {
            const int k0n = (kk + 1) * 64, nbuf = (kk + 1) & 1;
#pragma unroll
            for (int i = 0; i < 4; ++i) {
                const int row = srow + 32 * i;
                const int kb = skb0 ^ (row & 7);
                gload_lds16(OB + (size_t)(m0 + row) * 512 + k0n + kb * 8,
                            &Asm[nbuf][(wv * 64 + 256 * i) * 8]);
            }
#pragma unroll
            for (int i = 0; i < 2; ++i) {
                const int row = srow + 32 * i;
                const int kb = skb0 ^ (row & 7);
                gload_lds16(Wob + (size_t)(e0 + row) * 512 + k0n + kb * 8,
                            &Bsm[nbuf][(wv * 64 + 256 * i) * 8]);
            }
        }
        const int buf = kk & 1;
#pragma unroll
        for (int ks = 0; ks < 2; ++ks) {
            short8v af[4], bf[2];
#pragma unroll
            for (int mt = 0; mt < 4; ++mt) {
                const int row = wrow + mt * 16 + fm;
                af[mt] = *(const short8v*)&Asm[buf][row * 64 + 8 * ((4 * ks + fq) ^ (row & 7))];
            }
#pragma unroll
            for (int nt = 0; nt < 2; ++nt) {
                const int row = wcol + nt * 16 + fm;
                bf[nt] = *(const short8v*)&Bsm[buf][row * 64 + 8 * ((4 * ks + fq) ^ (row & 7))];
            }
#pragma unroll
            for (int mt = 0; mt < 4; ++mt)
#pragma unroll
                for (int nt = 0; nt < 2; ++nt)
                    acc[mt][nt] = __builtin_amdgcn_mfma_f32_16x16x32_bf16(af[mt], bf[nt], acc[mt][nt], 0, 0, 0);
        }
    }
#pragma unroll
    for (int mt = 0; mt < 4; ++mt)
#pragma unroll
        for (int nt = 0; nt < 2; ++nt)
#pragma unroll
            for (int r = 0; r < 4; ++r) {
                const int m = m0 + wrow + mt * 16 + 4 * fq + r;
                const int e = e0 + wcol + nt * 16 + fm;
                out[(size_t)m * 512 + e] = acc[mt][nt][r];
            }
}

// ---------------------------------------------------------------------------
extern "C" void kernel_launch(void* const* d_in, const int* in_sizes, int n_in,
                              void* d_out, int out_size, void* d_ws, size_t ws_size,
                              hipStream_t stream) {
    const float* x     = (const float*)d_in[0];   // [B,S,D]
    const float* w_qkv = (const float*)d_in[1];   // [3D, D]
    const float* w_out = (const float*)d_in[2];   // [D, D]
    float* out = (float*)d_out;                   // [B,S,D]

    // workspace carve-up (bytes): total ~61.4 MB
    char* p = (char*)d_ws;
    unsigned short* Xp  = (unsigned short*)p;  p += (size_t)M_ * 1024 * 2;      // 16.8 MB
    unsigned short* Wh  = (unsigned short*)p;  p += (size_t)1536 * 512 * 2;     // 1.6 MB
    unsigned short* Wlq = (unsigned short*)p;  p += (size_t)512 * 512 * 2;      // 0.5 MB
    unsigned short* Wob = (unsigned short*)p;  p += (size_t)512 * 512 * 2;      // 0.5 MB
    unsigned short* QmH = (unsigned short*)p;  p += (size_t)32 * S_ * 64 * 2;   // 8.4 MB
    unsigned short* QmL = (unsigned short*)p;  p += (size_t)32 * S_ * 64 * 2;
    unsigned short* Cc  = (unsigned short*)p;  p += (size_t)32 * S_ * 64 * 2;
    unsigned short* KH  = (unsigned short*)p;  p += (size_t)32 * S_ * 64 * 2;
    unsigned short* VT  = (unsigned short*)p;  p += (size_t)32 * 64 * S_ * 2;
    unsigned short* OB  = Xp;  // Xp dead after gemm_qkv; reuse for attention output

    prepass<<<2560, 256, 0, stream>>>(x, w_qkv, w_out, Xp, Wh, Wlq, Wob);
    gemm_qkv<<<dim3(32, 64), 256, 0, stream>>>(Xp, Wh, Wlq, QmH, QmL, Cc, KH, VT);
    attn<<<dim3(32, 32), 256, 0, stream>>>(QmH, QmL, Cc, KH, VT, OB);
    gemm_out<<<dim3(8, 64), 256, 0, stream>>>(OB, Wob, out);
}

// Round 2
// 195.072 us; speedup vs baseline: 1.0410x; 1.0410x over previous
//
#include <hip/hip_runtime.h>
#include <hip/hip_bf16.h>

// Problem dims (fixed by the reference)
constexpr int B_  = 4;
constexpr int S_  = 2048;
constexpr int D_  = 512;
constexpr int H_  = 8;
constexpr int HD_ = 64;
constexpr int M_  = B_ * S_;   // 8192

constexpr float LOG2E = 1.4426950408889634f;

typedef __attribute__((ext_vector_type(8))) short short8v;            // 8 bf16 (4 VGPR) MFMA operand
typedef __attribute__((ext_vector_type(4))) short short4v;            // 4 bf16 (2 VGPR) K=16 MFMA operand
typedef __attribute__((ext_vector_type(8))) _Float16 half8v;          // 8 f16 (4 VGPR) MFMA operand
typedef __attribute__((ext_vector_type(8))) unsigned short ushort8v;  // 16B staging chunk
typedef __attribute__((ext_vector_type(4))) float float4v;            // MFMA C/D

__device__ __forceinline__ unsigned short f2bf(float x) {  // RNE fp32->bf16
    unsigned u = __builtin_bit_cast(unsigned, x);
    u += 0x7fffu + ((u >> 16) & 1u);
    return (unsigned short)(u >> 16);
}
__device__ __forceinline__ float bf2f(unsigned short h) {
    return __builtin_bit_cast(float, ((unsigned)h) << 16);
}
__device__ __forceinline__ unsigned short f2h(float x) {   // RNE fp32->fp16 bits
    return __builtin_bit_cast(unsigned short, (_Float16)x);
}
__device__ __forceinline__ float fast_exp2(float x) {
#if __has_builtin(__builtin_amdgcn_exp2f)
    return __builtin_amdgcn_exp2f(x);
#else
    return exp2f(x);
#endif
}
// K=16 bf16 MFMA: A/B = 4 bf16 (2 VGPR), C/D = 4 f32. Lane layout:
//   A[row=l&15][k=(l>>4)*4+i], B[k=(l>>4)*4+i][col=l&15], C/D as 16x16x32.
__device__ __forceinline__ float4v mfma_16x16x16_bf16(short4v a, short4v b, float4v c) {
#if __has_builtin(__builtin_amdgcn_mfma_f32_16x16x16bf16_1k)
    return __builtin_amdgcn_mfma_f32_16x16x16bf16_1k(a, b, c, 0, 0, 0);
#elif __has_builtin(__builtin_amdgcn_mfma_f32_16x16x16_bf16)
    return __builtin_amdgcn_mfma_f32_16x16x16_bf16(a, b, c, 0, 0, 0);
#else
    asm volatile("v_mfma_f32_16x16x16_bf16 %0, %1, %2, %0" : "+v"(c) : "v"(a), "v"(b));
    return c;
#endif
}
// async global->LDS, 16B per lane; lds dest = wave-uniform base + lane*16
__device__ __forceinline__ void gload_lds16(const void* g, void* lds) {
    __builtin_amdgcn_global_load_lds((const __attribute__((address_space(1))) unsigned*)g,
                                     (__attribute__((address_space(3))) unsigned*)lds, 16, 0, 0);
}

// ---------------------------------------------------------------------------
// Prepass: build bf16 operands (R8 version).
//   Xp  [8192][1024]: cols [0:512)=hi(x), [512:1024)=lo(x)
//   Wh  [1536][512] : hi(w_qkv);  Wlq [512][512]: lo(w_q);  Wob: hi(w_out)
// ---------------------------------------------------------------------------
__global__ __launch_bounds__(256) void prepass(const float* __restrict__ x,
                                               const float* __restrict__ wqkv,
                                               const float* __restrict__ wout,
                                               unsigned short* __restrict__ Xp,
                                               unsigned short* __restrict__ Wh,
                                               unsigned short* __restrict__ Wlq,
                                               unsigned short* __restrict__ Wob) {
    const int bid = blockIdx.x, t = threadIdx.x;
    if (bid < 2048) {                      // x
        const int flat = bid * 256 + t;
        const int m = flat >> 6, c = (flat & 63) * 8;
        const float4 a = *(const float4*)&x[(size_t)m * 512 + c];
        const float4 b = *(const float4*)&x[(size_t)m * 512 + c + 4];
        const float v[8] = {a.x, a.y, a.z, a.w, b.x, b.y, b.z, b.w};
        ushort8v hi, lo;
#pragma unroll
        for (int i = 0; i < 8; ++i) {
            const unsigned short h = f2bf(v[i]);
            hi[i] = h; lo[i] = f2bf(v[i] - bf2f(h));
        }
        *(ushort8v*)&Xp[(size_t)m * 1024 + c]       = hi;
        *(ushort8v*)&Xp[(size_t)m * 1024 + 512 + c] = lo;
    } else if (bid < 2048 + 384) {         // w_qkv
        const int flat = (bid - 2048) * 256 + t;
        const int e = flat >> 6, c = (flat & 63) * 8;
        const float4 a = *(const float4*)&wqkv[(size_t)e * 512 + c];
        const float4 b = *(const float4*)&wqkv[(size_t)e * 512 + c + 4];
        const float v[8] = {a.x, a.y, a.z, a.w, b.x, b.y, b.z, b.w};
        ushort8v hi, lo;
#pragma unroll
        for (int i = 0; i < 8; ++i) {
            const unsigned short h = f2bf(v[i]);
            hi[i] = h; lo[i] = f2bf(v[i] - bf2f(h));
        }
        *(ushort8v*)&Wh[(size_t)e * 512 + c] = hi;
        if (e < 512) *(ushort8v*)&Wlq[(size_t)e * 512 + c] = lo;
    } else {                               // w_out
        const int flat = (bid - 2432) * 256 + t;
        const int e = flat >> 6, c = (flat & 63) * 8;
        const float4 a = *(const float4*)&wout[(size_t)e * 512 + c];
        const float4 b = *(const float4*)&wout[(size_t)e * 512 + c + 4];
        const float v[8] = {a.x, a.y, a.z, a.w, b.x, b.y, b.z, b.w};
        ushort8v hi;
#pragma unroll
        for (int i = 0; i < 8; ++i) hi[i] = f2bf(v[i]);
        *(ushort8v*)&Wob[(size_t)e * 512 + c] = hi;
    }
}

// ---------------------------------------------------------------------------
// GEMM1 (QKV projection): 128x64 tiles, BK=64, dbuf+prefetch, 1 barrier/iter.
// LDS 48 KB -> 3 blocks/CU; grid (32,64)=2048 blocks (8 blocks/CU of work).
// Slices: x>>3 = 0:qcorr(K=1024, dispatched first) 1:qmain 2:k 3:v (K=512).
// e0 = (x&7)*64 within the 512-wide segment.
// Wave layout: wrow=(wv>>1)*64, wcol=(wv&1)*32; acc[4][2].
// vblk: acc[mt][nt] = mfma(A=bf[nt], B=af[mt]) => D rows = e, cols = m.
// NOTE: K (slice 2) is stored as **f16** (attn QK^T runs f16 single-pass).
// ---------------------------------------------------------------------------
__global__ __launch_bounds__(256, 3) void gemm_qkv(const unsigned short* __restrict__ Xp,
                                                   const unsigned short* __restrict__ Wh,
                                                   const unsigned short* __restrict__ Wlq,
                                                   unsigned short* __restrict__ QmH,
                                                   unsigned short* __restrict__ QmL,
                                                   unsigned short* __restrict__ Cc,
                                                   unsigned short* __restrict__ KH,
                                                   unsigned short* __restrict__ VT) {
    __shared__ unsigned short Asm[2][128 * 64];   // 32 KB
    __shared__ unsigned short Bsm[2][64 * 64];    // 16 KB
    const int t = threadIdx.x, wv = t >> 6, lane = t & 63;
    const int fm = lane & 15, fq = lane >> 4;
    const int m0 = blockIdx.y * 128;
    const int x  = blockIdx.x;
    const int slice = x >> 3;            // 0=qcorr 1=qmain 2=k 3=v
    const int e0 = (x & 7) * 64;         // within the 512-wide segment
    const bool vblk = (slice == 3);
    const int kiters = (slice == 0) ? 16 : 8;
    const int wrow = (wv >> 1) * 64, wcol = (wv & 1) * 32;

    const unsigned short* BbaseWh =
        Wh + (size_t)(e0 + (slice == 2 ? 512 : (slice == 3 ? 1024 : 0))) * 512;
    const unsigned short* BbaseWlq = Wlq + (size_t)e0 * 512;

    const int srow = t >> 3;     // 0..31; +32*i extends
    const int skb0 = t & 7;

    float4v acc[4][2];
#pragma unroll
    for (int i = 0; i < 4; ++i)
#pragma unroll
        for (int j = 0; j < 2; ++j) acc[i][j] = (float4v){0.f, 0.f, 0.f, 0.f};

    // prologue: stage tile kk=0 into buf 0
    {
        const int aoff = (slice == 0) ? 512 : 0;   // qcorr pass0 uses XL
#pragma unroll
        for (int i = 0; i < 4; ++i) {
            const int row = srow + 32 * i;
            const int kb = skb0 ^ (row & 7);
            gload_lds16(Xp + (size_t)(m0 + row) * 1024 + aoff + kb * 8,
                        &Asm[0][(wv * 64 + 256 * i) * 8]);
        }
#pragma unroll
        for (int i = 0; i < 2; ++i) {
            const int row = srow + 32 * i;
            const int kb = skb0 ^ (row & 7);
            gload_lds16(BbaseWh + (size_t)row * 512 + kb * 8,
                        &Bsm[0][(wv * 64 + 256 * i) * 8]);
        }
    }

    for (int kk = 0; kk < kiters; ++kk) {
        __syncthreads();   // tile kk DMA complete; buf[(kk+1)&1] free

        if (kk + 1 < kiters) {     // prefetch tile kk+1 (overlaps compute of kk)
            const int nk = kk + 1;
            const int pass = nk >> 3;
            const int k0n = (nk & 7) * 64;
            const int nbuf = nk & 1;
            const int aoff = (slice == 0 && pass == 0) ? 512 : 0;
            const unsigned short* Bp = (slice == 0 && pass == 1) ? BbaseWlq : BbaseWh;
#pragma unroll
            for (int i = 0; i < 4; ++i) {
                const int row = srow + 32 * i;
                const int kb = skb0 ^ (row & 7);
                gload_lds16(Xp + (size_t)(m0 + row) * 1024 + aoff + k0n + kb * 8,
                            &Asm[nbuf][(wv * 64 + 256 * i) * 8]);
            }
#pragma unroll
            for (int i = 0; i < 2; ++i) {
                const int row = srow + 32 * i;
                const int kb = skb0 ^ (row & 7);
                gload_lds16(Bp + (size_t)row * 512 + k0n + kb * 8,
                            &Bsm[nbuf][(wv * 64 + 256 * i) * 8]);
            }
        }

        const int buf = kk & 1;
#pragma unroll
        for (int ks = 0; ks < 2; ++ks) {
            short8v af[4], bf[2];
#pragma unroll
            for (int mt = 0; mt < 4; ++mt) {
                const int row = wrow + mt * 16 + fm;
                af[mt] = *(const short8v*)&Asm[buf][row * 64 + 8 * ((4 * ks + fq) ^ (row & 7))];
            }
#pragma unroll
            for (int nt = 0; nt < 2; ++nt) {
                const int row = wcol + nt * 16 + fm;
                bf[nt] = *(const short8v*)&Bsm[buf][row * 64 + 8 * ((4 * ks + fq) ^ (row & 7))];
            }
            if (vblk) {
#pragma unroll
                for (int mt = 0; mt < 4; ++mt)
#pragma unroll
                    for (int nt = 0; nt < 2; ++nt)
                        acc[mt][nt] = __builtin_amdgcn_mfma_f32_16x16x32_bf16(bf[nt], af[mt], acc[mt][nt], 0, 0, 0);
            } else {
#pragma unroll
                for (int mt = 0; mt < 4; ++mt)
#pragma unroll
                    for (int nt = 0; nt < 2; ++nt)
                        acc[mt][nt] = __builtin_amdgcn_mfma_f32_16x16x32_bf16(af[mt], bf[nt], acc[mt][nt], 0, 0, 0);
            }
        }
    }

    if (slice == 1) {
        // qmain: hi/lo split store (acc rows = m-block mt, cols = e-block nt)
#pragma unroll
        for (int mt = 0; mt < 4; ++mt)
#pragma unroll
            for (int nt = 0; nt < 2; ++nt) {
                const int e = e0 + wcol + nt * 16 + fm;
                const int h = e >> 6, hd = e & 63;
#pragma unroll
                for (int r = 0; r < 4; ++r) {
                    const int m = m0 + wrow + mt * 16 + 4 * fq + r;
                    const int b = m >> 11, s = m & 2047;
                    const float v = acc[mt][nt][r];
                    const unsigned short hh = f2bf(v);
                    const size_t idx = ((size_t)(b * 8 + h) * 2048 + s) * 64 + hd;
                    QmH[idx] = hh;
                    QmL[idx] = f2bf(v - bf2f(hh));
                }
            }
    } else if (slice == 0 || slice == 2) {
        // qcorr: bf16 store; k: f16 store (attn QK^T is f16)
        unsigned short* __restrict__ dst = (slice == 0) ? Cc : KH;
#pragma unroll
        for (int mt = 0; mt < 4; ++mt)
#pragma unroll
            for (int nt = 0; nt < 2; ++nt) {
                const int e = e0 + wcol + nt * 16 + fm;
                const int h = e >> 6, hd = e & 63;
#pragma unroll
                for (int r = 0; r < 4; ++r) {
                    const int m = m0 + wrow + mt * 16 + 4 * fq + r;
                    const int b = m >> 11, s = m & 2047;
                    const float v = acc[mt][nt][r];
                    dst[((size_t)(b * 8 + h) * 2048 + s) * 64 + hd] =
                        (slice == 0) ? f2bf(v) : f2h(v);
                }
            }
    } else {
        // v: acc[mt][nt] rows = e-block nt (4fq+r), cols = m-block mt (fm)
#pragma unroll
        for (int nt = 0; nt < 2; ++nt)
#pragma unroll
            for (int r = 0; r < 4; ++r) {
                const int e = e0 + wcol + nt * 16 + 4 * fq + r;
                const int h = e >> 6, hd = e & 63;
#pragma unroll
                for (int mt = 0; mt < 4; ++mt) {
                    const int m = m0 + wrow + mt * 16 + fm;
                    const int b = m >> 11, s = m & 2047;
                    VT[((size_t)(b * 8 + h) * 64 + hd) * 2048 + s] = f2bf(acc[mt][nt][r]);
                }
            }
    }
}

// ---------------------------------------------------------------------------
// MFMA flash attention v3 (LDS-bandwidth-focused restructure).
// Block = (bh, 128 q-rows), 4 waves x 32 q; grid (16,32)=512 blocks = 2/CU.
// Rationale: v2 was LDS-BW-bound (per block-iter: 64KB K/V reads + 16KB Ph
// round-trip + 16KB DMA ~ 750cy vs 466cy MFMA; 4 blocks share one LDS port).
// v3: (a) 32 q/wave -> K/V LDS reads serve 2x the output (frags reused in
// regs across qt); (b) PV via 16x16x16 bf16 MFMA whose A-layout matches the
// swapped-QK^T S layout lane-exactly -> P never touches LDS (Ph eliminated,
// LDS 40->32KB); (c) QK^T in f16 single-pass (8 MFMA, was 16 bf16 hi/lo) --
// f16 on both q,k is MORE accurate than hi/lo-q x bf16-k. P stays trunc-bf16
// (exp2(S) can exceed f16 range). Balance now ~640cy LDS vs ~620cy MFMA.
// ---------------------------------------------------------------------------
__global__ __launch_bounds__(256, 2) void attn(const unsigned short* __restrict__ QmHp,
                                               const unsigned short* __restrict__ QmLp,
                                               const unsigned short* __restrict__ Ccp,
                                               const unsigned short* __restrict__ KHp,
                                               const unsigned short* __restrict__ VTp,
                                               unsigned short* __restrict__ OB) {
    __shared__ unsigned short Ks[2][64 * 64];    // 16 KB, f16 K tile [j][d], XOR-swizzled
    __shared__ unsigned short Vs[2][64 * 64];    // 16 KB, bf16 V^T tile [d][j], XOR-swizzled
    const int t = threadIdx.x, wv = t >> 6, lane = t & 63;
    const int fm = lane & 15, fq = lane >> 4;
    const int bh = blockIdx.y, q0 = blockIdx.x * 128;

    const unsigned short* qmh = QmHp + (size_t)bh * S_ * 64;
    const unsigned short* qml = QmLp + (size_t)bh * S_ * 64;
    const unsigned short* qcc = Ccp  + (size_t)bh * S_ * 64;
    const unsigned short* kh  = KHp  + (size_t)bh * S_ * 64;
    const unsigned short* vt  = VTp  + (size_t)bh * 64 * S_;

    const int srow = t >> 3;
    const int skb0 = t & 7;

    // prologue: stage K/V tile jt=0 into buf 0
#pragma unroll
    for (int i = 0; i < 2; ++i) {
        const int row = srow + 32 * i;
        const int kb = skb0 ^ (row & 7);
        const int dst = (wv * 64 + 256 * i) * 8;
        gload_lds16(kh + (size_t)row * 64 + kb * 8, &Ks[0][dst]);
        gload_lds16(vt + (size_t)row * S_ + kb * 8, &Vs[0][dst]);
    }

    // Q fragments (f16, single-pass): q = (Qm + C) * log2e, rows qw+qt*16+fm.
    half8v qf[2][2];
    {
        const int qw = q0 + wv * 32;
#pragma unroll
        for (int qt = 0; qt < 2; ++qt)
#pragma unroll
            for (int t2 = 0; t2 < 2; ++t2) {
                const size_t off = (size_t)(qw + qt * 16 + fm) * 64 + t2 * 32 + fq * 8;
                const ushort8v mh = *(const ushort8v*)&qmh[off];
                const ushort8v ml = *(const ushort8v*)&qml[off];
                const ushort8v cc = *(const ushort8v*)&qcc[off];
#pragma unroll
                for (int i = 0; i < 8; ++i) {
                    const float v = (bf2f(mh[i]) + bf2f(ml[i]) + bf2f(cc[i])) * LOG2E;
                    qf[qt][t2][i] = (_Float16)v;
                }
            }
    }

    float4v accO[2][4];
#pragma unroll
    for (int qt = 0; qt < 2; ++qt)
#pragma unroll
        for (int dt = 0; dt < 4; ++dt) accO[qt][dt] = (float4v){0.f, 0.f, 0.f, 0.f};
    float lsum[2] = {0.f, 0.f};

    for (int jt = 0; jt < 32; ++jt) {
        __syncthreads();   // tile jt DMA complete (barrier drains vmcnt); buf[(jt+1)&1] free

        if (jt + 1 < 32) {
            const int j0n = (jt + 1) * 64;
            const int nbuf = (jt + 1) & 1;
#pragma unroll
            for (int i = 0; i < 2; ++i) {
                const int row = srow + 32 * i;
                const int kb = skb0 ^ (row & 7);
                const int dst = (wv * 64 + 256 * i) * 8;
                gload_lds16(kh + (size_t)(j0n + row) * 64 + kb * 8, &Ks[nbuf][dst]);
                gload_lds16(vt + (size_t)row * S_ + j0n + kb * 8, &Vs[nbuf][dst]);
            }
        }
        const int buf = jt & 1;

        // S^T = K Q^T (swapped, f16): lane holds S[q=fm(+qt*16)][j=st*16+4fq+r]
        float4v accS[2][4];
#pragma unroll
        for (int qt = 0; qt < 2; ++qt)
#pragma unroll
            for (int st = 0; st < 4; ++st) accS[qt][st] = (float4v){0.f, 0.f, 0.f, 0.f};
        __builtin_amdgcn_s_setprio(1);
#pragma unroll
        for (int t2 = 0; t2 < 2; ++t2)
#pragma unroll
            for (int st = 0; st < 4; ++st) {
                const int row = st * 16 + fm;
                const half8v kf = *(const half8v*)&Ks[buf][row * 64 + 8 * ((4 * t2 + fq) ^ (row & 7))];
#pragma unroll
                for (int qt = 0; qt < 2; ++qt)
                    accS[qt][st] = __builtin_amdgcn_mfma_f32_16x16x32_f16(kf, qf[qt][t2], accS[qt][st], 0, 0, 0);
            }
        __builtin_amdgcn_s_setprio(0);

        // P = exp2(S), accumulate l, pack lane-local to bf16x4 (K=16 A-frag:
        // A[q=fm][k=4fq+i] == P[fm][16st+4fq+i] -- exactly what this lane holds)
        short4v pa[2][4];
#pragma unroll
        for (int qt = 0; qt < 2; ++qt)
#pragma unroll
            for (int st = 0; st < 4; ++st) {
                const float p0 = fast_exp2(accS[qt][st][0]);
                const float p1 = fast_exp2(accS[qt][st][1]);
                const float p2 = fast_exp2(accS[qt][st][2]);
                const float p3 = fast_exp2(accS[qt][st][3]);
                lsum[qt] += (p0 + p1) + (p2 + p3);
                uint2 w;
                w.x = (__builtin_bit_cast(unsigned, p1) & 0xffff0000u) |
                      (__builtin_bit_cast(unsigned, p0) >> 16);
                w.y = (__builtin_bit_cast(unsigned, p3) & 0xffff0000u) |
                      (__builtin_bit_cast(unsigned, p2) >> 16);
                pa[qt][st] = __builtin_bit_cast(short4v, w);
            }

        // O += P V via 16x16x16 MFMA; V frags (b64) reused across qt.
        __builtin_amdgcn_s_setprio(1);
#pragma unroll
        for (int st = 0; st < 4; ++st) {
            const int cb = 2 * st + (fq >> 1);    // col block of j = st*16+4fq
            const int co = 4 * (fq & 1);          // offset within 8-elem block
#pragma unroll
            for (int dt = 0; dt < 4; ++dt) {
                const int vrow = dt * 16 + fm;
                const short4v vf =
                    *(const short4v*)&Vs[buf][vrow * 64 + ((cb ^ (vrow & 7)) << 3) + co];
#pragma unroll
                for (int qt = 0; qt < 2; ++qt)
                    accO[qt][dt] = mfma_16x16x16_bf16(pa[qt][st], vf, accO[qt][dt]);
            }
        }
        __builtin_amdgcn_s_setprio(0);
    }

    // l totals: lane holds partial for row q=fm; reduce over fq (lane bits 4,5)
    float ls[2];
#pragma unroll
    for (int qt = 0; qt < 2; ++qt) {
        float v = lsum[qt];
        v += __shfl_xor(v, 16);
        v += __shfl_xor(v, 32);
        ls[qt] = v;
    }

    // epilogue: accO[qt][dt][r] = O[q_local=qt*16+4fq+r][d=dt*16+fm]
    const int b = bh >> 3, h = bh & 7;
#pragma unroll
    for (int qt = 0; qt < 2; ++qt)
#pragma unroll
        for (int r = 0; r < 4; ++r) {
            const float inv = 1.f / __shfl(ls[qt], 4 * fq + r);
            const int q = q0 + wv * 32 + qt * 16 + 4 * fq + r;
#pragma unroll
            for (int dt = 0; dt < 4; ++dt)
                OB[((size_t)(b * 2048 + q)) * 512 + h * 64 + dt * 16 + fm] =
                    f2bf(accO[qt][dt][r] * inv);
        }
}

// ---------------------------------------------------------------------------
// GEMM2 (out projection), R8 version: 128x64 tile, dbuf + prefetch.
// ---------------------------------------------------------------------------
__global__ __launch_bounds__(256) void gemm_out(const unsigned short* __restrict__ OB,
                                                const unsigned short* __restrict__ Wob,
                                                float* __restrict__ out) {
    __shared__ unsigned short Asm[2][128 * 64];
    __shared__ unsigned short Bsm[2][64 * 64];
    const int t = threadIdx.x, wv = t >> 6, lane = t & 63;
    const int fm = lane & 15, fq = lane >> 4;
    const int m0 = blockIdx.y * 128, e0 = blockIdx.x * 64;
    const int wrow = (wv & 1) * 64, wcol = (wv >> 1) * 32;

    const int srow = t >> 3;
    const int skb0 = t & 7;

    float4v acc[4][2];
#pragma unroll
    for (int i = 0; i < 4; ++i)
#pragma unroll
        for (int j = 0; j < 2; ++j) acc[i][j] = (float4v){0.f, 0.f, 0.f, 0.f};

    // prologue: stage k0=0
#pragma unroll
    for (int i = 0; i < 4; ++i) {
        const int row = srow + 32 * i;
        const int kb = skb0 ^ (row & 7);
        gload_lds16(OB + (size_t)(m0 + row) * 512 + kb * 8,
                    &Asm[0][(wv * 64 + 256 * i) * 8]);
    }
#pragma unroll
    for (int i = 0; i < 2; ++i) {
        const int row = srow + 32 * i;
        const int kb = skb0 ^ (row & 7);
        gload_lds16(Wob + (size_t)(e0 + row) * 512 + kb * 8,
                    &Bsm[0][(wv * 64 + 256 * i) * 8]);
    }

    for (int kk = 0; kk < 8; ++kk) {
        __syncthreads();
        if (kk + 1 < 8) {
            const int k0n = (kk + 1) * 64, nbuf = (kk + 1) & 1;
#pragma unroll
            for (int i = 0; i < 4; ++i) {
                const int row = srow + 32 * i;
                const int kb = skb0 ^ (row & 7);
                gload_lds16(OB + (size_t)(m0 + row) * 512 + k0n + kb * 8,
                            &Asm[nbuf][(wv * 64 + 256 * i) * 8]);
            }
#pragma unroll
            for (int i = 0; i < 2; ++i) {
                const int row = srow + 32 * i;
                const int kb = skb0 ^ (row & 7);
                gload_lds16(Wob + (size_t)(e0 + row) * 512 + k0n + kb * 8,
                            &Bsm[nbuf][(wv * 64 + 256 * i) * 8]);
            }
        }
        const int buf = kk & 1;
#pragma unroll
        for (int ks = 0; ks < 2; ++ks) {
            short8v af[4], bf[2];
#pragma unroll
            for (int mt = 0; mt < 4; ++mt) {
                const int row = wrow + mt * 16 + fm;
                af[mt] = *(const short8v*)&Asm[buf][row * 64 + 8 * ((4 * ks + fq) ^ (row & 7))];
            }
#pragma unroll
            for (int nt = 0; nt < 2; ++nt) {
                const int row = wcol + nt * 16 + fm;
                bf[nt] = *(const short8v*)&Bsm[buf][row * 64 + 8 * ((4 * ks + fq) ^ (row & 7))];
            }
#pragma unroll
            for (int mt = 0; mt < 4; ++mt)
#pragma unroll
                for (int nt = 0; nt < 2; ++nt)
                    acc[mt][nt] = __builtin_amdgcn_mfma_f32_16x16x32_bf16(af[mt], bf[nt], acc[mt][nt], 0, 0, 0);
        }
    }
#pragma unroll
    for (int mt = 0; mt < 4; ++mt)
#pragma unroll
        for (int nt = 0; nt < 2; ++nt)
#pragma unroll
            for (int r = 0; r < 4; ++r) {
                const int m = m0 + wrow + mt * 16 + 4 * fq + r;
                const int e = e0 + wcol + nt * 16 + fm;
                out[(size_t)m * 512 + e] = acc[mt][nt][r];
            }
}

// ---------------------------------------------------------------------------
extern "C" void kernel_launch(void* const* d_in, const int* in_sizes, int n_in,
                              void* d_out, int out_size, void* d_ws, size_t ws_size,
                              hipStream_t stream) {
    const float* x     = (const float*)d_in[0];   // [B,S,D]
    const float* w_qkv = (const float*)d_in[1];   // [3D, D]
    const float* w_out = (const float*)d_in[2];   // [D, D]
    float* out = (float*)d_out;                   // [B,S,D]

    // workspace carve-up (bytes): total ~61.4 MB
    char* p = (char*)d_ws;
    unsigned short* Xp  = (unsigned short*)p;  p += (size_t)M_ * 1024 * 2;      // 16.8 MB
    unsigned short* Wh  = (unsigned short*)p;  p += (size_t)1536 * 512 * 2;     // 1.6 MB
    unsigned short* Wlq = (unsigned short*)p;  p += (size_t)512 * 512 * 2;      // 0.5 MB
    unsigned short* Wob = (unsigned short*)p;  p += (size_t)512 * 512 * 2;      // 0.5 MB
    unsigned short* QmH = (unsigned short*)p;  p += (size_t)32 * S_ * 64 * 2;   // 8.4 MB
    unsigned short* QmL = (unsigned short*)p;  p += (size_t)32 * S_ * 64 * 2;
    unsigned short* Cc  = (unsigned short*)p;  p += (size_t)32 * S_ * 64 * 2;
    unsigned short* KH  = (unsigned short*)p;  p += (size_t)32 * S_ * 64 * 2;   // f16
    unsigned short* VT  = (unsigned short*)p;  p += (size_t)32 * 64 * S_ * 2;
    unsigned short* OB  = Xp;  // Xp dead after gemm_qkv; reuse for attention output

    prepass<<<2560, 256, 0, stream>>>(x, w_qkv, w_out, Xp, Wh, Wlq, Wob);
    gemm_qkv<<<dim3(32, 64), 256, 0, stream>>>(Xp, Wh, Wlq, QmH, QmL, Cc, KH, VT);
    attn<<<dim3(16, 32), 256, 0, stream>>>(QmH, QmL, Cc, KH, VT, OB);
    gemm_out<<<dim3(8, 64), 256, 0, stream>>>(OB, Wob, out);
}

// Round 3
// 192.107 us; speedup vs baseline: 1.0571x; 1.0154x over previous
//
#include <hip/hip_runtime.h>
#include <hip/hip_bf16.h>

// Problem dims (fixed by the reference)
constexpr int B_  = 4;
constexpr int S_  = 2048;
constexpr int D_  = 512;
constexpr int H_  = 8;
constexpr int HD_ = 64;
constexpr int M_  = B_ * S_;   // 8192

constexpr float LOG2E = 1.4426950408889634f;

typedef __attribute__((ext_vector_type(8))) short short8v;            // 8 bf16 (4 VGPR) MFMA operand
typedef __attribute__((ext_vector_type(8))) _Float16 half8v;          // 8 f16 (4 VGPR) MFMA operand
typedef __attribute__((ext_vector_type(8))) unsigned short ushort8v;  // 16B staging chunk
typedef __attribute__((ext_vector_type(4))) float float4v;            // 16x16 MFMA C/D
typedef __attribute__((ext_vector_type(16))) float float16v;          // 32x32 MFMA C/D

__device__ __forceinline__ unsigned short f2bf(float x) {  // RNE fp32->bf16
    unsigned u = __builtin_bit_cast(unsigned, x);
    u += 0x7fffu + ((u >> 16) & 1u);
    return (unsigned short)(u >> 16);
}
__device__ __forceinline__ float bf2f(unsigned short h) {
    return __builtin_bit_cast(float, ((unsigned)h) << 16);
}
__device__ __forceinline__ unsigned short f2h(float x) {   // RNE fp32->fp16 bits
    return __builtin_bit_cast(unsigned short, (_Float16)x);
}
__device__ __forceinline__ float fast_exp2(float x) {
#if __has_builtin(__builtin_amdgcn_exp2f)
    return __builtin_amdgcn_exp2f(x);
#else
    return exp2f(x);
#endif
}
// pack two f32 as [trunc-bf16(lo) | trunc-bf16(hi)<<16]  (1 v_perm)
__device__ __forceinline__ unsigned pack_bf16_trunc(float lo, float hi) {
    const unsigned ulo = __builtin_bit_cast(unsigned, lo);
    const unsigned uhi = __builtin_bit_cast(unsigned, hi);
#if __has_builtin(__builtin_amdgcn_perm)
    return __builtin_amdgcn_perm(uhi, ulo, 0x07060302u);
#else
    return (uhi & 0xffff0000u) | (ulo >> 16);
#endif
}
// async global->LDS, 16B per lane; lds dest = wave-uniform base + lane*16
__device__ __forceinline__ void gload_lds16(const void* g, void* lds) {
    __builtin_amdgcn_global_load_lds((const __attribute__((address_space(1))) unsigned*)g,
                                     (__attribute__((address_space(3))) unsigned*)lds, 16, 0, 0);
}

// ---------------------------------------------------------------------------
// Prepass: build bf16 operands (R8 version).
//   Xp  [8192][1024]: cols [0:512)=hi(x), [512:1024)=lo(x)
//   Wh  [1536][512] : hi(w_qkv);  Wlq [512][512]: lo(w_q);  Wob: hi(w_out)
// ---------------------------------------------------------------------------
__global__ __launch_bounds__(256) void prepass(const float* __restrict__ x,
                                               const float* __restrict__ wqkv,
                                               const float* __restrict__ wout,
                                               unsigned short* __restrict__ Xp,
                                               unsigned short* __restrict__ Wh,
                                               unsigned short* __restrict__ Wlq,
                                               unsigned short* __restrict__ Wob) {
    const int bid = blockIdx.x, t = threadIdx.x;
    if (bid < 2048) {                      // x
        const int flat = bid * 256 + t;
        const int m = flat >> 6, c = (flat & 63) * 8;
        const float4 a = *(const float4*)&x[(size_t)m * 512 + c];
        const float4 b = *(const float4*)&x[(size_t)m * 512 + c + 4];
        const float v[8] = {a.x, a.y, a.z, a.w, b.x, b.y, b.z, b.w};
        ushort8v hi, lo;
#pragma unroll
        for (int i = 0; i < 8; ++i) {
            const unsigned short h = f2bf(v[i]);
            hi[i] = h; lo[i] = f2bf(v[i] - bf2f(h));
        }
        *(ushort8v*)&Xp[(size_t)m * 1024 + c]       = hi;
        *(ushort8v*)&Xp[(size_t)m * 1024 + 512 + c] = lo;
    } else if (bid < 2048 + 384) {         // w_qkv
        const int flat = (bid - 2048) * 256 + t;
        const int e = flat >> 6, c = (flat & 63) * 8;
        const float4 a = *(const float4*)&wqkv[(size_t)e * 512 + c];
        const float4 b = *(const float4*)&wqkv[(size_t)e * 512 + c + 4];
        const float v[8] = {a.x, a.y, a.z, a.w, b.x, b.y, b.z, b.w};
        ushort8v hi, lo;
#pragma unroll
        for (int i = 0; i < 8; ++i) {
            const unsigned short h = f2bf(v[i]);
            hi[i] = h; lo[i] = f2bf(v[i] - bf2f(h));
        }
        *(ushort8v*)&Wh[(size_t)e * 512 + c] = hi;
        if (e < 512) *(ushort8v*)&Wlq[(size_t)e * 512 + c] = lo;
    } else {                               // w_out
        const int flat = (bid - 2432) * 256 + t;
        const int e = flat >> 6, c = (flat & 63) * 8;
        const float4 a = *(const float4*)&wout[(size_t)e * 512 + c];
        const float4 b = *(const float4*)&wout[(size_t)e * 512 + c + 4];
        const float v[8] = {a.x, a.y, a.z, a.w, b.x, b.y, b.z, b.w};
        ushort8v hi;
#pragma unroll
        for (int i = 0; i < 8; ++i) hi[i] = f2bf(v[i]);
        *(ushort8v*)&Wob[(size_t)e * 512 + c] = hi;
    }
}

// ---------------------------------------------------------------------------
// GEMM1 (QKV projection): 128x64 tiles, BK=64, dbuf+prefetch, 1 barrier/iter.
// LDS 48 KB -> 3 blocks/CU; grid (32,64)=2048 blocks (8 blocks/CU of work).
// Slices: x>>3 = 0:qcorr(K=1024, dispatched first) 1:qmain 2:k 3:v (K=512).
// e0 = (x&7)*64 within the 512-wide segment.
// Wave layout: wrow=(wv>>1)*64, wcol=(wv&1)*32; acc[4][2].
// vblk: acc[mt][nt] = mfma(A=bf[nt], B=af[mt]) => D rows = e, cols = m.
// NOTE: K (slice 2) is stored as **f16** (attn QK^T runs f16 single-pass).
// ---------------------------------------------------------------------------
__global__ __launch_bounds__(256, 3) void gemm_qkv(const unsigned short* __restrict__ Xp,
                                                   const unsigned short* __restrict__ Wh,
                                                   const unsigned short* __restrict__ Wlq,
                                                   unsigned short* __restrict__ QmH,
                                                   unsigned short* __restrict__ QmL,
                                                   unsigned short* __restrict__ Cc,
                                                   unsigned short* __restrict__ KH,
                                                   unsigned short* __restrict__ VT) {
    __shared__ unsigned short Asm[2][128 * 64];   // 32 KB
    __shared__ unsigned short Bsm[2][64 * 64];    // 16 KB
    const int t = threadIdx.x, wv = t >> 6, lane = t & 63;
    const int fm = lane & 15, fq = lane >> 4;
    const int m0 = blockIdx.y * 128;
    const int x  = blockIdx.x;
    const int slice = x >> 3;            // 0=qcorr 1=qmain 2=k 3=v
    const int e0 = (x & 7) * 64;         // within the 512-wide segment
    const bool vblk = (slice == 3);
    const int kiters = (slice == 0) ? 16 : 8;
    const int wrow = (wv >> 1) * 64, wcol = (wv & 1) * 32;

    const unsigned short* BbaseWh =
        Wh + (size_t)(e0 + (slice == 2 ? 512 : (slice == 3 ? 1024 : 0))) * 512;
    const unsigned short* BbaseWlq = Wlq + (size_t)e0 * 512;

    const int srow = t >> 3;     // 0..31; +32*i extends
    const int skb0 = t & 7;

    float4v acc[4][2];
#pragma unroll
    for (int i = 0; i < 4; ++i)
#pragma unroll
        for (int j = 0; j < 2; ++j) acc[i][j] = (float4v){0.f, 0.f, 0.f, 0.f};

    // prologue: stage tile kk=0 into buf 0
    {
        const int aoff = (slice == 0) ? 512 : 0;   // qcorr pass0 uses XL
#pragma unroll
        for (int i = 0; i < 4; ++i) {
            const int row = srow + 32 * i;
            const int kb = skb0 ^ (row & 7);
            gload_lds16(Xp + (size_t)(m0 + row) * 1024 + aoff + kb * 8,
                        &Asm[0][(wv * 64 + 256 * i) * 8]);
        }
#pragma unroll
        for (int i = 0; i < 2; ++i) {
            const int row = srow + 32 * i;
            const int kb = skb0 ^ (row & 7);
            gload_lds16(BbaseWh + (size_t)row * 512 + kb * 8,
                        &Bsm[0][(wv * 64 + 256 * i) * 8]);
        }
    }

    for (int kk = 0; kk < kiters; ++kk) {
        __syncthreads();   // tile kk DMA complete; buf[(kk+1)&1] free

        if (kk + 1 < kiters) {     // prefetch tile kk+1 (overlaps compute of kk)
            const int nk = kk + 1;
            const int pass = nk >> 3;
            const int k0n = (nk & 7) * 64;
            const int nbuf = nk & 1;
            const int aoff = (slice == 0 && pass == 0) ? 512 : 0;
            const unsigned short* Bp = (slice == 0 && pass == 1) ? BbaseWlq : BbaseWh;
#pragma unroll
            for (int i = 0; i < 4; ++i) {
                const int row = srow + 32 * i;
                const int kb = skb0 ^ (row & 7);
                gload_lds16(Xp + (size_t)(m0 + row) * 1024 + aoff + k0n + kb * 8,
                            &Asm[nbuf][(wv * 64 + 256 * i) * 8]);
            }
#pragma unroll
            for (int i = 0; i < 2; ++i) {
                const int row = srow + 32 * i;
                const int kb = skb0 ^ (row & 7);
                gload_lds16(Bp + (size_t)row * 512 + k0n + kb * 8,
                            &Bsm[nbuf][(wv * 64 + 256 * i) * 8]);
            }
        }

        const int buf = kk & 1;
#pragma unroll
        for (int ks = 0; ks < 2; ++ks) {
            short8v af[4], bf[2];
#pragma unroll
            for (int mt = 0; mt < 4; ++mt) {
                const int row = wrow + mt * 16 + fm;
                af[mt] = *(const short8v*)&Asm[buf][row * 64 + 8 * ((4 * ks + fq) ^ (row & 7))];
            }
#pragma unroll
            for (int nt = 0; nt < 2; ++nt) {
                const int row = wcol + nt * 16 + fm;
                bf[nt] = *(const short8v*)&Bsm[buf][row * 64 + 8 * ((4 * ks + fq) ^ (row & 7))];
            }
            if (vblk) {
#pragma unroll
                for (int mt = 0; mt < 4; ++mt)
#pragma unroll
                    for (int nt = 0; nt < 2; ++nt)
                        acc[mt][nt] = __builtin_amdgcn_mfma_f32_16x16x32_bf16(bf[nt], af[mt], acc[mt][nt], 0, 0, 0);
            } else {
#pragma unroll
                for (int mt = 0; mt < 4; ++mt)
#pragma unroll
                    for (int nt = 0; nt < 2; ++nt)
                        acc[mt][nt] = __builtin_amdgcn_mfma_f32_16x16x32_bf16(af[mt], bf[nt], acc[mt][nt], 0, 0, 0);
            }
        }
    }

    if (slice == 1) {
        // qmain: hi/lo split store (acc rows = m-block mt, cols = e-block nt)
#pragma unroll
        for (int mt = 0; mt < 4; ++mt)
#pragma unroll
            for (int nt = 0; nt < 2; ++nt) {
                const int e = e0 + wcol + nt * 16 + fm;
                const int h = e >> 6, hd = e & 63;
#pragma unroll
                for (int r = 0; r < 4; ++r) {
                    const int m = m0 + wrow + mt * 16 + 4 * fq + r;
                    const int b = m >> 11, s = m & 2047;
                    const float v = acc[mt][nt][r];
                    const unsigned short hh = f2bf(v);
                    const size_t idx = ((size_t)(b * 8 + h) * 2048 + s) * 64 + hd;
                    QmH[idx] = hh;
                    QmL[idx] = f2bf(v - bf2f(hh));
                }
            }
    } else if (slice == 0 || slice == 2) {
        // qcorr: bf16 store; k: f16 store (attn QK^T is f16)
        unsigned short* __restrict__ dst = (slice == 0) ? Cc : KH;
#pragma unroll
        for (int mt = 0; mt < 4; ++mt)
#pragma unroll
            for (int nt = 0; nt < 2; ++nt) {
                const int e = e0 + wcol + nt * 16 + fm;
                const int h = e >> 6, hd = e & 63;
#pragma unroll
                for (int r = 0; r < 4; ++r) {
                    const int m = m0 + wrow + mt * 16 + 4 * fq + r;
                    const int b = m >> 11, s = m & 2047;
                    const float v = acc[mt][nt][r];
                    dst[((size_t)(b * 8 + h) * 2048 + s) * 64 + hd] =
                        (slice == 0) ? f2bf(v) : f2h(v);
                }
            }
    } else {
        // v: acc[mt][nt] rows = e-block nt (4fq+r), cols = m-block mt (fm)
#pragma unroll
        for (int nt = 0; nt < 2; ++nt)
#pragma unroll
            for (int r = 0; r < 4; ++r) {
                const int e = e0 + wcol + nt * 16 + 4 * fq + r;
                const int h = e >> 6, hd = e & 63;
#pragma unroll
                for (int mt = 0; mt < 4; ++mt) {
                    const int m = m0 + wrow + mt * 16 + fm;
                    const int b = m >> 11, s = m & 2047;
                    VT[((size_t)(b * 8 + h) * 64 + hd) * 2048 + s] = f2bf(acc[mt][nt][r]);
                }
            }
    }
}

// ---------------------------------------------------------------------------
// MFMA flash attention v4: full-rate 32x32x16 for BOTH GEMMs.
// v3 post-mortem: 16x16x16 PV MFMAs occupy full K=32 pipe slots at half FLOPs
// (MfmaUtil arithmetic: 16 cyc/instr per SIMD = full-rate 16x16x32 cost), and
// the b64 V-reads stacked 4 addrs/bank (2^22 conflict counter). v4:
//  - Wave = one 32-q block (4 waves = BQ 128). QK^T swapped via
//    mfma_32x32x16_f16(A=K[32j x 16d], B=Q[16d x 32q]) x 8 -> lane holds
//    S[q=lane&31][j = (reg&3)+8*(reg>>2)+4*(lane>>5)].
//  - P: exp2 -> pack bf16x2 dwords (v_perm) -> half-wave exchange via
//    pre-select + shfl_xor(32) (8 shfls) -> exact 32x32x16 A-frag
//    P[q=lane&31][j=8*(lane>>5)+i] per 16-j chunk. P never touches LDS.
//  - PV: mfma_32x32x16_bf16(A=P, B=V^T[16j x 32d]) x 8, b128 V-reads (even
//    bank spread). MFMA pipe per wave-iter: 772 -> 516 SIMD-cyc, same FLOPs.
//  - lsum is lane-local (q=lane&31): one shfl_xor(32) at the end.
// LDS 32 KB (K f16 + V bf16, dbuf); grid (16,32)=512 blocks = 2/CU (grid-
// limited); floors/CU: MFMA 13.8us, LDS 13.4us, VALU ~10us.
// ---------------------------------------------------------------------------
__global__ __launch_bounds__(256, 2) void attn(const unsigned short* __restrict__ QmHp,
                                               const unsigned short* __restrict__ QmLp,
                                               const unsigned short* __restrict__ Ccp,
                                               const unsigned short* __restrict__ KHp,
                                               const unsigned short* __restrict__ VTp,
                                               unsigned short* __restrict__ OB) {
    __shared__ unsigned short Ks[2][64 * 64];    // 16 KB, f16 K tile [j][d], XOR-swizzled
    __shared__ unsigned short Vs[2][64 * 64];    // 16 KB, bf16 V^T tile [d][j], XOR-swizzled
    const int t = threadIdx.x, wv = t >> 6, lane = t & 63;
    const int lq = lane & 31;     // q (and d/j) index within 32
    const int hf2 = lane >> 5;    // half-wave
    const int bh = blockIdx.y, q0 = blockIdx.x * 128;

    const unsigned short* qmh = QmHp + (size_t)bh * S_ * 64;
    const unsigned short* qml = QmLp + (size_t)bh * S_ * 64;
    const unsigned short* qcc = Ccp  + (size_t)bh * S_ * 64;
    const unsigned short* kh  = KHp  + (size_t)bh * S_ * 64;
    const unsigned short* vt  = VTp  + (size_t)bh * 64 * S_;

    const int srow = t >> 3;
    const int skb0 = t & 7;

    // prologue: stage K/V tile jt=0 into buf 0
#pragma unroll
    for (int i = 0; i < 2; ++i) {
        const int row = srow + 32 * i;
        const int kb = skb0 ^ (row & 7);
        const int dst = (wv * 64 + 256 * i) * 8;
        gload_lds16(kh + (size_t)row * 64 + kb * 8, &Ks[0][dst]);
        gload_lds16(vt + (size_t)row * S_ + kb * 8, &Vs[0][dst]);
    }

    // Q B-frags (f16): lane holds Q[q = q0+wv*32+lq][d = kk*16 + hf2*8 + i]
    half8v qf[4];
    {
        const int qrow = q0 + wv * 32 + lq;
#pragma unroll
        for (int kk = 0; kk < 4; ++kk) {
            const size_t off = (size_t)qrow * 64 + kk * 16 + hf2 * 8;
            const ushort8v mh = *(const ushort8v*)&qmh[off];
            const ushort8v ml = *(const ushort8v*)&qml[off];
            const ushort8v cc = *(const ushort8v*)&qcc[off];
#pragma unroll
            for (int i = 0; i < 8; ++i)
                qf[kk][i] = (_Float16)((bf2f(mh[i]) + bf2f(ml[i]) + bf2f(cc[i])) * LOG2E);
        }
    }

    float16v accO[2];
#pragma unroll
    for (int db = 0; db < 2; ++db)
#pragma unroll
        for (int r = 0; r < 16; ++r) accO[db][r] = 0.f;
    float lsum = 0.f;

    for (int jt = 0; jt < 32; ++jt) {
        __syncthreads();   // tile jt DMA complete (barrier drains vmcnt); buf[(jt+1)&1] free

        if (jt + 1 < 32) {
            const int j0n = (jt + 1) * 64;
            const int nbuf = (jt + 1) & 1;
#pragma unroll
            for (int i = 0; i < 2; ++i) {
                const int row = srow + 32 * i;
                const int kb = skb0 ^ (row & 7);
                const int dst = (wv * 64 + 256 * i) * 8;
                gload_lds16(kh + (size_t)(j0n + row) * 64 + kb * 8, &Ks[nbuf][dst]);
                gload_lds16(vt + (size_t)row * S_ + j0n + kb * 8, &Vs[nbuf][dst]);
            }
        }
        const int buf = jt & 1;

        // S^T = K Q^T: accS[jb] over j-block jb; lane: q=lq, j=jb*32+(reg&3)+8*(reg>>2)+4*hf2
        float16v accS[2];
#pragma unroll
        for (int jb = 0; jb < 2; ++jb)
#pragma unroll
            for (int r = 0; r < 16; ++r) accS[jb][r] = 0.f;
        __builtin_amdgcn_s_setprio(1);
#pragma unroll
        for (int kk = 0; kk < 4; ++kk)
#pragma unroll
            for (int jb = 0; jb < 2; ++jb) {
                const int row = jb * 32 + lq;
                const int cb = 2 * kk + hf2;
                const half8v kf = *(const half8v*)&Ks[buf][row * 64 + 8 * (cb ^ (row & 7))];
                accS[jb] = __builtin_amdgcn_mfma_f32_32x32x16_f16(kf, qf[kk], accS[jb], 0, 0, 0);
            }
        __builtin_amdgcn_s_setprio(0);

        // P = exp2(S); pack to bf16x2 dwords pk[jb][g][w] covering local
        // j' = (w*2 + {0,1}) + 8g + 4*hf2 within jb's 32; accumulate lsum.
        unsigned pk[2][4][2];
#pragma unroll
        for (int jb = 0; jb < 2; ++jb)
#pragma unroll
            for (int g = 0; g < 4; ++g) {
                const float p0 = fast_exp2(accS[jb][4 * g + 0]);
                const float p1 = fast_exp2(accS[jb][4 * g + 1]);
                const float p2 = fast_exp2(accS[jb][4 * g + 2]);
                const float p3 = fast_exp2(accS[jb][4 * g + 3]);
                lsum += (p0 + p1) + (p2 + p3);
                pk[jb][g][0] = pack_bf16_trunc(p0, p1);
                pk[jb][g][1] = pack_bf16_trunc(p2, p3);
            }

        // Half-wave exchange: h=0 lanes need partner's pk[g even], h=1 lanes
        // need partner's pk[g odd]  (partner = lane^32, same q).
        unsigned xw[2][2][2];
#pragma unroll
        for (int jb = 0; jb < 2; ++jb)
#pragma unroll
            for (int hf = 0; hf < 2; ++hf)
#pragma unroll
                for (int w = 0; w < 2; ++w) {
                    const unsigned snd = hf2 ? pk[jb][2 * hf][w] : pk[jb][2 * hf + 1][w];
                    xw[jb][hf][w] = (unsigned)__shfl_xor((int)snd, 32);
                }

        // O += P V: A-frag for j-chunk jc: P[q=lq][j = jc*16 + hf2*8 + i]
        __builtin_amdgcn_s_setprio(1);
#pragma unroll
        for (int jc = 0; jc < 4; ++jc) {
            const int jb = jc >> 1, hf = jc & 1;
            const unsigned d0 = hf2 ? xw[jb][hf][0] : pk[jb][2 * hf][0];
            const unsigned d1 = hf2 ? xw[jb][hf][1] : pk[jb][2 * hf][1];
            const unsigned d2 = hf2 ? pk[jb][2 * hf + 1][0] : xw[jb][hf][0];
            const unsigned d3 = hf2 ? pk[jb][2 * hf + 1][1] : xw[jb][hf][1];
            const uint4 uu = {d0, d1, d2, d3};
            const short8v pa = __builtin_bit_cast(short8v, uu);
#pragma unroll
            for (int db = 0; db < 2; ++db) {
                const int vrow = db * 32 + lq;
                const int cb = 2 * jc + hf2;
                const short8v vf = *(const short8v*)&Vs[buf][vrow * 64 + 8 * (cb ^ (vrow & 7))];
                accO[db] = __builtin_amdgcn_mfma_f32_32x32x16_bf16(pa, vf, accO[db], 0, 0, 0);
            }
        }
        __builtin_amdgcn_s_setprio(0);
    }

    // lane holds l-partial for q=lq over its half of j; combine halves
    const float ls = lsum + __shfl_xor(lsum, 32);
    const float invl = 1.f / ls;

    // epilogue: accO[db][4g+r] = O[q_local=r+8g+4*hf2][d=db*32+lq]
    const int b = bh >> 3, hh = bh & 7;
#pragma unroll
    for (int g = 0; g < 4; ++g)
#pragma unroll
        for (int r = 0; r < 4; ++r) {
            const int qrow = r + 8 * g + 4 * hf2;
            const float inv = __shfl(invl, qrow);   // lane qrow holds q=qrow
            const int q = q0 + wv * 32 + qrow;
#pragma unroll
            for (int db = 0; db < 2; ++db)
                OB[((size_t)(b * 2048 + q)) * 512 + hh * 64 + db * 32 + lq] =
                    f2bf(accO[db][4 * g + r] * inv);
        }
}

// ---------------------------------------------------------------------------
// GEMM2 (out projection), R8 version: 128x64 tile, dbuf + prefetch.
// ---------------------------------------------------------------------------
__global__ __launch_bounds__(256) void gemm_out(const unsigned short* __restrict__ OB,
                                                const unsigned short* __restrict__ Wob,
                                                float* __restrict__ out) {
    __shared__ unsigned short Asm[2][128 * 64];
    __shared__ unsigned short Bsm[2][64 * 64];
    const int t = threadIdx.x, wv = t >> 6, lane = t & 63;
    const int fm = lane & 15, fq = lane >> 4;
    const int m0 = blockIdx.y * 128, e0 = blockIdx.x * 64;
    const int wrow = (wv & 1) * 64, wcol = (wv >> 1) * 32;

    const int srow = t >> 3;
    const int skb0 = t & 7;

    float4v acc[4][2];
#pragma unroll
    for (int i = 0; i < 4; ++i)
#pragma unroll
        for (int j = 0; j < 2; ++j) acc[i][j] = (float4v){0.f, 0.f, 0.f, 0.f};

    // prologue: stage k0=0
#pragma unroll
    for (int i = 0; i < 4; ++i) {
        const int row = srow + 32 * i;
        const int kb = skb0 ^ (row & 7);
        gload_lds16(OB + (size_t)(m0 + row) * 512 + kb * 8,
                    &Asm[0][(wv * 64 + 256 * i) * 8]);
    }
#pragma unroll
    for (int i = 0; i < 2; ++i) {
        const int row = srow + 32 * i;
        const int kb = skb0 ^ (row & 7);
        gload_lds16(Wob + (size_t)(e0 + row) * 512 + kb * 8,
                    &Bsm[0][(wv * 64 + 256 * i) * 8]);
    }

    for (int kk = 0; kk < 8; ++kk) {
        __syncthreads();
        if (kk + 1 < 8) {
            const int k0n = (kk + 1) * 64, nbuf = (kk + 1) & 1;
#pragma unroll
            for (int i = 0; i < 4; ++i) {
                const int row = srow + 32 * i;
                const int kb = skb0 ^ (row & 7);
                gload_lds16(OB + (size_t)(m0 + row) * 512 + k0n + kb * 8,
                            &Asm[nbuf][(wv * 64 + 256 * i) * 8]);
            }
#pragma unroll
            for (int i = 0; i < 2; ++i) {
                const int row = srow + 32 * i;
                const int kb = skb0 ^ (row & 7);
                gload_lds16(Wob + (size_t)(e0 + row) * 512 + k0n + kb * 8,
                            &Bsm[nbuf][(wv * 64 + 256 * i) * 8]);
            }
        }
        const int buf = kk & 1;
#pragma unroll
        for (int ks = 0; ks < 2; ++ks) {
            short8v af[4], bf[2];
#pragma unroll
            for (int mt = 0; mt < 4; ++mt) {
                const int row = wrow + mt * 16 + fm;
                af[mt] = *(const short8v*)&Asm[buf][row * 64 + 8 * ((4 * ks + fq) ^ (row & 7))];
            }
#pragma unroll
            for (int nt = 0; nt < 2; ++nt) {
                const int row = wcol + nt * 16 + fm;
                bf[nt] = *(const short8v*)&Bsm[buf][row * 64 + 8 * ((4 * ks + fq) ^ (row & 7))];
            }
#pragma unroll
            for (int mt = 0; mt < 4; ++mt)
#pragma unroll
                for (int nt = 0; nt < 2; ++nt)
                    acc[mt][nt] = __builtin_amdgcn_mfma_f32_16x16x32_bf16(af[mt], bf[nt], acc[mt][nt], 0, 0, 0);
        }
    }
#pragma unroll
    for (int mt = 0; mt < 4; ++mt)
#pragma unroll
        for (int nt = 0; nt < 2; ++nt)
#pragma unroll
            for (int r = 0; r < 4; ++r) {
                const int m = m0 + wrow + mt * 16 + 4 * fq + r;
                const int e = e0 + wcol + nt * 16 + fm;
                out[(size_t)m * 512 + e] = acc[mt][nt][r];
            }
}

// ---------------------------------------------------------------------------
extern "C" void kernel_launch(void* const* d_in, const int* in_sizes, int n_in,
                              void* d_out, int out_size, void* d_ws, size_t ws_size,
                              hipStream_t stream) {
    const float* x     = (const float*)d_in[0];   // [B,S,D]
    const float* w_qkv = (const float*)d_in[1];   // [3D, D]
    const float* w_out = (const float*)d_in[2];   // [D, D]
    float* out = (float*)d_out;                   // [B,S,D]

    // workspace carve-up (bytes): total ~61.4 MB
    char* p = (char*)d_ws;
    unsigned short* Xp  = (unsigned short*)p;  p += (size_t)M_ * 1024 * 2;      // 16.8 MB
    unsigned short* Wh  = (unsigned short*)p;  p += (size_t)1536 * 512 * 2;     // 1.6 MB
    unsigned short* Wlq = (unsigned short*)p;  p += (size_t)512 * 512 * 2;      // 0.5 MB
    unsigned short* Wob = (unsigned short*)p;  p += (size_t)512 * 512 * 2;      // 0.5 MB
    unsigned short* QmH = (unsigned short*)p;  p += (size_t)32 * S_ * 64 * 2;   // 8.4 MB
    unsigned short* QmL = (unsigned short*)p;  p += (size_t)32 * S_ * 64 * 2;
    unsigned short* Cc  = (unsigned short*)p;  p += (size_t)32 * S_ * 64 * 2;
    unsigned short* KH  = (unsigned short*)p;  p += (size_t)32 * S_ * 64 * 2;   // f16
    unsigned short* VT  = (unsigned short*)p;  p += (size_t)32 * 64 * S_ * 2;
    unsigned short* OB  = Xp;  // Xp dead after gemm_qkv; reuse for attention output

    prepass<<<2560, 256, 0, stream>>>(x, w_qkv, w_out, Xp, Wh, Wlq, Wob);
    gemm_qkv<<<dim3(32, 64), 256, 0, stream>>>(Xp, Wh, Wlq, QmH, QmL, Cc, KH, VT);
    attn<<<dim3(16, 32), 256, 0, stream>>>(QmH, QmL, Cc, KH, VT, OB);
    gemm_out<<<dim3(8, 64), 256, 0, stream>>>(OB, Wob, out);
}